// Round 2
// baseline (670.570 us; speedup 1.0000x reference)
//
#include <hip/hip_runtime.h>

// Problem constants (from reference):
//   B=256, C=8, M=16, N=4096, R=D=64, CM=C*M=128
//   outputs[b,n] = sum_cm x[b,cm,n] * w[cm]          (512 MiB in, 4 MiB out)
//   idx = argmax_n outputs[b,:]  (first-max tiebreak)
//   r = trunc(r_target[idx/64]); d = trunc(d_target[idx%64])
//   flat out = [outputs (B*N), d (B), r (B), d (B)]
//
// R2 change (structural): R0/R1 used one 1024-thread block per batch row.
// That shape (a) hard-caps VGPRs at 128 (4 waves/SIMD mandatory), and
// (b) both variants staged loads in v4f arrays under aggressive unrolling,
// inviting the scheduler to hoist far more loads than the register budget
// allows -> scratch spills -> ~3x HBM traffic (313 us kernel, 1.7 TB/s,
// identical across two different loop shapes = schedule-insensitive =
// traffic-bound, not schedule-bound).
//
// New shape: 256-thread blocks, 4 column-slices per batch row (1024 blocks,
// up to 8 blocks/CU = 32 waves/CU), row-group loop kept as a COMPACT
// NON-UNROLLED loop (#pragma unroll 1): 8 in-flight dwordx4 loads/wave,
// ~60 VGPRs, statically-indexed staging (no scratch). Per-block partial
// argmax goes to d_ws; a tiny finalize kernel reduces 4 partials/batch.

#define BATCH   256
#define NDIM    4096
#define CM      128
#define SLICES  4
#define SLICE_COLS (NDIM / SLICES)      // 1024
#define THREADS1   (SLICE_COLS / 4)     // 256 threads, 4 cols each
#define NWAVES1    (THREADS1 / 64)      // 4
#define GROUP   8
#define NGROUPS (CM / GROUP)            // 16

typedef float v4f __attribute__((ext_vector_type(4)));  // clang-native for nontemporal builtin

__global__ __launch_bounds__(THREADS1) void conv_partial_kernel(
    const float* __restrict__ x, const float* __restrict__ W,
    float* __restrict__ out, float2* __restrict__ partial)
{
    __shared__ float w[CM];
    __shared__ float sval[NWAVES1];
    __shared__ int   sidx[NWAVES1];

    const int blk = blockIdx.x;
    const int b   = blk >> 2;           // / SLICES
    const int s   = blk & (SLICES - 1);
    const int tid = threadIdx.x;

    if (tid < CM) w[tid] = W[tid];
    __syncthreads();

    const int n0 = s * SLICE_COLS + tid * 4;        // this thread's 4 columns
    const float* xp = x + (size_t)b * (CM * NDIM) + n0;

    float acc0 = 0.f, acc1 = 0.f, acc2 = 0.f, acc3 = 0.f;

    // Compact loop: 8 loads in flight -> 8 FMA rows. unroll 1 keeps register
    // demand bounded (~32 staging VGPRs) so nothing spills; 32 waves/CU give
    // 256 KiB/CU in flight, >> the ~10 KiB BW-delay product.
    #pragma unroll 1
    for (int g = 0; g < NGROUPS; ++g) {
        v4f v[GROUP];
        #pragma unroll
        for (int j = 0; j < GROUP; ++j) {
            v[j] = __builtin_nontemporal_load(
                (const v4f*)(xp + (size_t)(g * GROUP + j) * NDIM));
        }
        #pragma unroll
        for (int j = 0; j < GROUP; ++j) {
            const float wc = w[g * GROUP + j];      // uniform ds_read broadcast
            acc0 += v[j].x * wc;
            acc1 += v[j].y * wc;
            acc2 += v[j].z * wc;
            acc3 += v[j].w * wc;
        }
    }

    v4f o;
    o.x = acc0; o.y = acc1; o.z = acc2; o.w = acc3;
    __builtin_nontemporal_store(o, (v4f*)(out + (size_t)b * NDIM + n0));

    // Thread-local argmax (ascending index => first-occurrence tiebreak).
    float bv = acc0; int bi = n0;
    if (acc1 > bv) { bv = acc1; bi = n0 + 1; }
    if (acc2 > bv) { bv = acc2; bi = n0 + 2; }
    if (acc3 > bv) { bv = acc3; bi = n0 + 3; }

    // Wave (64-lane) reduction: larger value wins; equal -> smaller index.
    for (int off = 32; off >= 1; off >>= 1) {
        float ov = __shfl_down(bv, off, 64);
        int   oi = __shfl_down(bi, off, 64);
        if (ov > bv || (ov == bv && oi < bi)) { bv = ov; bi = oi; }
    }
    const int wave = tid >> 6;
    if ((tid & 63) == 0) { sval[wave] = bv; sidx[wave] = bi; }
    __syncthreads();

    if (tid == 0) {
        #pragma unroll
        for (int i = 1; i < NWAVES1; ++i) {
            if (sval[i] > bv || (sval[i] == bv && sidx[i] < bi)) {
                bv = sval[i]; bi = sidx[i];
            }
        }
        partial[blk] = make_float2(bv, __int_as_float(bi));
    }
}

// One block, 256 threads: thread b merges its batch's 4 slice-partials
// (ascending slice order preserves first-occurrence tiebreak) and writes
// the 3 tail outputs.
__global__ __launch_bounds__(256) void finalize_kernel(
    const float2* __restrict__ partial,
    const float* __restrict__ r_target, const float* __restrict__ d_target,
    float* __restrict__ out)
{
    const int b = threadIdx.x;
    float2 p = partial[b * SLICES];
    float bv = p.x;
    int   bi = __float_as_int(p.y);
    #pragma unroll
    for (int s = 1; s < SLICES; ++s) {
        float2 q = partial[b * SLICES + s];
        const int qi = __float_as_int(q.y);
        if (q.x > bv || (q.x == bv && qi < bi)) { bv = q.x; bi = qi; }
    }
    const int r_index = bi >> 6;        // idx // 64  (len_r == 64)
    const int d_index = bi & 63;        // idx % 64   (len_d == 64)
    // Reference assigns float into int tensor: truncation toward zero.
    const float r = (float)(int)r_target[r_index];
    const float d = (float)(int)d_target[d_index];
    const int BN = BATCH * NDIM;
    out[BN + b]             = d;        // second return element: d
    out[BN + BATCH + b]     = r;        // output tuple: r
    out[BN + 2 * BATCH + b] = d;        // output tuple: d
}

extern "C" void kernel_launch(void* const* d_in, const int* in_sizes, int n_in,
                              void* d_out, int out_size, void* d_ws, size_t ws_size,
                              hipStream_t stream) {
    const float* x        = (const float*)d_in[0];  // [B, C, M, N] = [256,8,16,4096]
    const float* W        = (const float*)d_in[1];  // [1, C, M, 1] -> 128 floats, idx c*16+m
    const float* r_target = (const float*)d_in[2];  // [64]
    const float* d_target = (const float*)d_in[3];  // [64]
    float* out = (float*)d_out;
    float2* partial = (float2*)d_ws;                // 1024 * 8 B = 8 KiB

    conv_partial_kernel<<<BATCH * SLICES, THREADS1, 0, stream>>>(x, W, out, partial);
    finalize_kernel<<<1, 256, 0, stream>>>(partial, r_target, d_target, out);
}